// Round 7
// baseline (1823.339 us; speedup 1.0000x reference)
//
#include <hip/hip_runtime.h>

#define USH unsigned short
#define AGENT __HIP_MEMORY_SCOPE_AGENT
typedef __attribute__((ext_vector_type(8))) short short8;
typedef __attribute__((ext_vector_type(4))) float f32x4;

__device__ __forceinline__ USH rne_bf16(float f){
  unsigned int u = __float_as_uint(f);
  u = (u + 0x7fffu + ((u >> 16) & 1u)) >> 16;
  return (USH)u;
}
__device__ __forceinline__ float sigm(float x){ return 1.f / (1.f + __expf(-x)); }
__device__ __forceinline__ float tanh_(float x){ return 1.f - 2.f / (__expf(2.f * x) + 1.f); }
__device__ __forceinline__ void gload16(const void* g, void* l){
  __builtin_amdgcn_global_load_lds((const __attribute__((address_space(1))) unsigned int*)g,
                                   (__attribute__((address_space(3))) unsigned int*)l, 16, 0, 0);
}
// agent-coherent (write-through past XCD L2) 2-byte store
__device__ __forceinline__ void st_bf16_sc1(USH* p, USH v){
  asm volatile("global_store_short %0, %1, off sc1" :: "v"(p), "v"((unsigned int)v) : "memory");
}
#define MFMA __builtin_amdgcn_mfma_f32_16x16x32_bf16

// ---- prep: Wc = W_ih1 @ W_lin packed frag-major, bc = W_ih1@b_lin + b_ih1 + b_hh1
__global__ void k_fold(const float* __restrict__ Wih1, const float* __restrict__ Wlin,
                       const float* __restrict__ blin, const float* __restrict__ bih1,
                       const float* __restrict__ bhh1, USH* __restrict__ Wcpk, float* __restrict__ bc){
  const int n = blockIdx.x;          // 0..4095 gate-row
  const int t = threadIdx.x;
  float a[34];
#pragma unroll
  for (int f = 0; f < 34; ++f) a[f] = 0.f;
  float ab = 0.f;
  for (int e = t; e < 1024; e += 64){
    const float wv = Wih1[n * 1024 + e];
    ab += wv * blin[e];
    const float* wl = Wlin + e * 34;
#pragma unroll
    for (int f = 0; f < 34; ++f) a[f] += wv * wl[f];
  }
#pragma unroll
  for (int off = 32; off > 0; off >>= 1){
    ab += __shfl_down(ab, off);
#pragma unroll
    for (int f = 0; f < 34; ++f) a[f] += __shfl_down(a[f], off);
  }
  if (t == 0){
    const int nc = n & 1023, gq = n >> 10, cgi = nc >> 4, lp = nc & 15;
    for (int f = 0; f < 64; ++f){
      const float v = (f < 34) ? a[f] : 0.f;
      const int lane = lp + (((f >> 3) & 3) << 4);
      const int idx = (((cgi * 2 + (f >> 5)) * 4 + gq) * 64 + lane) * 8 + (f & 7);
      Wcpk[idx] = rne_bf16(v);
    }
    bc[n] = ab + bih1[n] + bhh1[n];
  }
}

// ---- prep: pack 3 weight matrices into frag-major bf16 [cg][ks][gq][lane][8]; b2
__global__ void k_pack(const float* __restrict__ Whh1, const float* __restrict__ Wih2,
                       const float* __restrict__ Whh2, const float* __restrict__ bih2,
                       const float* __restrict__ bhh2,
                       USH* __restrict__ P1, USH* __restrict__ P2a, USH* __restrict__ P2b,
                       float* __restrict__ ob2){
  const int N = 4096 * 1024;
  for (int i = blockIdx.x * blockDim.x + threadIdx.x; i < N; i += gridDim.x * blockDim.x){
    const int j = i & 7, li = (i >> 3) & 63, gq = (i >> 9) & 3, ks = (i >> 11) & 31, cgi = i >> 16;
    const int n = gq * 1024 + cgi * 16 + (li & 15);
    const int k = ks * 32 + ((li >> 4) << 3) + j;
    const int src = n * 1024 + k;
    P1[i]  = rne_bf16(Whh1[src]);
    P2a[i] = rne_bf16(Wih2[src]);
    P2b[i] = rne_bf16(Whh2[src]);
    if (i < 4096) ob2[i] = bih2[i] + bhh2[i];
  }
}

// ---- prep: x [B][T][34] fp32 -> frag-major bf16 xp[t][g][ks2][lane][8] (K padded to 64)
__global__ void k_xpk(const float* __restrict__ x, USH* __restrict__ xp){
  const int N = 100 * 16384;
  for (int i = blockIdx.x * blockDim.x + threadIdx.x; i < N; i += gridDim.x * blockDim.x){
    const int j = i & 7, li = (i >> 3) & 63, ks = (i >> 9) & 1, g = (i >> 10) & 15, t = i >> 14;
    const int row = g * 16 + (li & 15);
    const int f = ks * 32 + ((li >> 4) << 3) + j;
    xp[i] = (f < 34) ? rne_bf16(x[(row * 100 + t) * 34 + f]) : (USH)0;
  }
}

// ---- persistent: 256 WGs x 256 thr. wg<128: L1 (cg=wg>>1, mh=wg&1); else L2.
__global__ __launch_bounds__(256) void k_persist(
    USH* __restrict__ hA1, USH* __restrict__ hA2,
    int* __restrict__ ctrA, int* __restrict__ ctrB,
    const USH* __restrict__ Wpk1, const USH* __restrict__ Wpk2a, const USH* __restrict__ Wpk2b,
    const USH* __restrict__ Wcpk, const USH* __restrict__ xpk,
    const float* __restrict__ bc, const float* __restrict__ b2, float* __restrict__ out,
    int d1, int d2, int useFence)
{
  __shared__ __attribute__((aligned(16))) char lds[131072];
  const int tid = threadIdx.x, w = tid >> 6, l = tid & 63;
  const int wg = blockIdx.x;
  const int isL2 = wg >> 7;
  const int cg = (wg & 127) >> 1;
  const int mh = wg & 1;
  const int gb = mh * 8 + w * 2;
  const int col = cg * 16 + (l & 15);
  const int lofs16 = l * 16;
  const int lofs8 = l * 8;

  const int ks2 = cg >> 1;
  const int l16 = (cg * 2 + ((l & 15) >> 3)) & 3;
  const int j2 = l & 7;

  float creg[2][4];
#pragma unroll
  for (int mf = 0; mf < 2; ++mf)
#pragma unroll
    for (int r = 0; r < 4; ++r) creg[mf][r] = 0.f;

  if (!isL2){
    // ================= L1 role: free-running serial recurrence =================
    const USH* s = Wpk1 + (size_t)cg * 65536;              // Whh1 slice, 128 KB
#pragma unroll
    for (int r = 0; r < 32; ++r)
      gload16(s + (r * 4 + w) * 512 + lofs8, &lds[(r * 4 + w) * 1024]);
    short8 wc[2][4];
#pragma unroll
    for (int ks = 0; ks < 2; ++ks)
#pragma unroll
      for (int gq = 0; gq < 4; ++gq)
        wc[ks][gq] = *(const short8*)(Wcpk + (size_t)cg * 4096 + (ks * 4 + gq) * 512 + lofs8);
    __syncthreads();
    const float bi0 = bc[col], bi1 = bc[1024 + col], bi2 = bc[2048 + col], bi3 = bc[3072 + col];

    for (int p = 0; p < 100; ++p){
      if (p >= 1){
        if (tid == 0){
          while (__hip_atomic_load(ctrA, __ATOMIC_RELAXED, AGENT) < 128 * p)
            __builtin_amdgcn_s_sleep(1);
          if (useFence){
            while (__hip_atomic_load(ctrB, __ATOMIC_RELAXED, AGENT) < 128 * (p - 2))
              __builtin_amdgcn_s_sleep(1);
            __builtin_amdgcn_fence(__ATOMIC_ACQUIRE, "agent");
          }
        }
        __syncthreads();
      }
      f32x4 acc[2][4];
#pragma unroll
      for (int mf = 0; mf < 2; ++mf)
#pragma unroll
        for (int gq = 0; gq < 4; ++gq) acc[mf][gq] = (f32x4){0.f, 0.f, 0.f, 0.f};

      if (p > 0){
        const USH* Ap = hA1 + (size_t)((p - 1) % d1) * 262144 + gb * 16384 + lofs8;
#pragma unroll
        for (int ks = 0; ks < 32; ++ks){
          short8 a0 = *(const short8*)(Ap + ks * 512);
          short8 a1 = *(const short8*)(Ap + 16384 + ks * 512);
          const char* bb = &lds[ks * 4096 + lofs16];
#pragma unroll
          for (int gq = 0; gq < 4; ++gq){
            short8 bf = *(const short8*)(bb + gq * 1024);
            acc[0][gq] = MFMA(a0, bf, acc[0][gq], 0, 0, 0);
            acc[1][gq] = MFMA(a1, bf, acc[1][gq], 0, 0, 0);
          }
        }
      }
      const USH* Xp = xpk + (size_t)p * 16384 + gb * 1024 + lofs8;
#pragma unroll
      for (int ks = 0; ks < 2; ++ks){
        short8 a0 = *(const short8*)(Xp + ks * 512);
        short8 a1 = *(const short8*)(Xp + 1024 + ks * 512);
#pragma unroll
        for (int gq = 0; gq < 4; ++gq){
          acc[0][gq] = MFMA(a0, wc[ks][gq], acc[0][gq], 0, 0, 0);
          acc[1][gq] = MFMA(a1, wc[ks][gq], acc[1][gq], 0, 0, 0);
        }
      }
      USH* hn = hA1 + (size_t)(p % d1) * 262144;
#pragma unroll
      for (int mf = 0; mf < 2; ++mf){
        const int g2 = gb + mf;
#pragma unroll
        for (int r = 0; r < 4; ++r){
          const float gi = acc[mf][0][r] + bi0;
          const float gf = acc[mf][1][r] + bi1;
          const float gg = acc[mf][2][r] + bi2;
          const float go = acc[mf][3][r] + bi3;
          const float cn = sigm(gf) * creg[mf][r] + sigm(gi) * tanh_(gg);
          creg[mf][r] = cn;
          const int lane2 = ((l >> 4) << 2) + r + (l16 << 4);
          st_bf16_sc1(&hn[(g2 * 32 + ks2) * 512 + lane2 * 8 + j2], rne_bf16(sigm(go) * tanh_(cn)));
        }
      }
      asm volatile("s_waitcnt vmcnt(0)" ::: "memory");
      __syncthreads();
      if (tid == 0){
        if (useFence) __builtin_amdgcn_fence(__ATOMIC_RELEASE, "agent");
        __hip_atomic_fetch_add(ctrA, 1, __ATOMIC_RELAXED, AGENT);
      }
    }
  } else {
    // ================= L2 role: streams behind L1 =================
    const USH* s = Wpk2b + (size_t)cg * 65536;             // Whh2 ks0..23, 96 KB resident
#pragma unroll
    for (int r = 0; r < 24; ++r)
      gload16(s + (r * 4 + w) * 512 + lofs8, &lds[(r * 4 + w) * 1024]);
    __syncthreads();
    const float bi0 = b2[col], bi1 = b2[1024 + col], bi2 = b2[2048 + col], bi3 = b2[3072 + col];
    const USH* Wsa = Wpk2a + (size_t)cg * 65536;
    const USH* Wsb = Wpk2b + (size_t)cg * 65536;

    for (int p = 1; p <= 100; ++p){
      // prestage chunk 0 (Wih2 ks0..3) — phase-independent, overlaps the spin
#pragma unroll
      for (int r = 0; r < 4; ++r)
        gload16(Wsa + (r * 4 + w) * 512 + lofs8, &lds[98304 + (r * 4 + w) * 1024]);
      if (tid == 0){
        while (__hip_atomic_load(ctrA, __ATOMIC_RELAXED, AGENT) < 128 * p)
          __builtin_amdgcn_s_sleep(1);
        while (__hip_atomic_load(ctrB, __ATOMIC_RELAXED, AGENT) < 128 * (p - 1))
          __builtin_amdgcn_s_sleep(1);
        if (useFence) __builtin_amdgcn_fence(__ATOMIC_ACQUIRE, "agent");
      }
      __syncthreads();                         // releases waves; also drains prestage

      const USH* A1p = hA1 + (size_t)((p - 1) % d1) * 262144 + gb * 16384 + lofs8;
      const USH* A2p = hA2 + (size_t)((p - 1) % d2) * 262144 + gb * 16384 + lofs8;

      f32x4 acc[2][4];
#pragma unroll
      for (int mf = 0; mf < 2; ++mf)
#pragma unroll
        for (int gq = 0; gq < 4; ++gq) acc[mf][gq] = (f32x4){0.f, 0.f, 0.f, 0.f};

      // chunks 0..7 = Wih2 (A=h1), 8..9 = Whh2 ks24..31 (A=h2); resident ks interleaved
      short8 ar[2][8];
#pragma unroll
      for (int kk = 0; kk < 4; ++kk){
        ar[0][kk * 2]     = *(const short8*)(A1p + kk * 512);
        ar[0][kk * 2 + 1] = *(const short8*)(A1p + 16384 + kk * 512);
      }
#pragma unroll
      for (int c = 0; c < 10; ++c){
        if (c) __syncthreads();                // staged chunk c + its A-regs complete
        if (c < 9){
          const int t = c + 1;
          const USH* src = (t < 8) ? (Wsa + t * 8192) : (Wsb + (t - 2) * 8192);
          char* dst = &lds[98304 + (t & 1) * 16384];
#pragma unroll
          for (int r = 0; r < 4; ++r)
            gload16(src + (r * 4 + w) * 512 + lofs8, dst + (r * 4 + w) * 1024);
          const USH* Ab = (t < 8) ? A1p : A2p;
          const int ksb = (t < 8) ? t * 4 : (t - 2) * 4;
#pragma unroll
          for (int kk = 0; kk < 4; ++kk){
            ar[t & 1][kk * 2]     = *(const short8*)(Ab + (ksb + kk) * 512);
            ar[t & 1][kk * 2 + 1] = *(const short8*)(Ab + 16384 + (ksb + kk) * 512);
          }
        }
        // issue this chunk's resident A-loads early (consumed after staged MFMAs)
        const int rb = (c < 8) ? 2 * c : 16 + 4 * (c - 8);
        const int rn = (c < 8) ? 2 : 4;
        short8 ra[4][2];
#pragma unroll
        for (int q = 0; q < 4; ++q){
          if (q < rn){
            ra[q][0] = *(const short8*)(A2p + (rb + q) * 512);
            ra[q][1] = *(const short8*)(A2p + 16384 + (rb + q) * 512);
          }
        }
        // staged compute: chunk c (4 ks from staging LDS)
        const char* cb = &lds[98304 + (c & 1) * 16384 + lofs16];
#pragma unroll
        for (int kk = 0; kk < 4; ++kk){
#pragma unroll
          for (int gq = 0; gq < 4; ++gq){
            short8 bf = *(const short8*)(cb + kk * 4096 + gq * 1024);
            acc[0][gq] = MFMA(ar[c & 1][kk * 2],     bf, acc[0][gq], 0, 0, 0);
            acc[1][gq] = MFMA(ar[c & 1][kk * 2 + 1], bf, acc[1][gq], 0, 0, 0);
          }
        }
        // resident compute: interleaved ks (B from resident LDS)
#pragma unroll
        for (int q = 0; q < 4; ++q){
          if (q < rn){
            const char* bb = &lds[(rb + q) * 4096 + lofs16];
#pragma unroll
            for (int gq = 0; gq < 4; ++gq){
              short8 bf = *(const short8*)(bb + gq * 1024);
              acc[0][gq] = MFMA(ra[q][0], bf, acc[0][gq], 0, 0, 0);
              acc[1][gq] = MFMA(ra[q][1], bf, acc[1][gq], 0, 0, 0);
            }
          }
        }
      }

      if (p < 100){
        USH* hn = hA2 + (size_t)(p % d2) * 262144;
#pragma unroll
        for (int mf = 0; mf < 2; ++mf){
          const int g2 = gb + mf;
#pragma unroll
          for (int r = 0; r < 4; ++r){
            const float gi = acc[mf][0][r] + bi0;
            const float gf = acc[mf][1][r] + bi1;
            const float gg = acc[mf][2][r] + bi2;
            const float go = acc[mf][3][r] + bi3;
            const float cn = sigm(gf) * creg[mf][r] + sigm(gi) * tanh_(gg);
            creg[mf][r] = cn;
            const int lane2 = ((l >> 4) << 2) + r + (l16 << 4);
            st_bf16_sc1(&hn[(g2 * 32 + ks2) * 512 + lane2 * 8 + j2], rne_bf16(sigm(go) * tanh_(cn)));
          }
        }
      } else {
#pragma unroll
        for (int mf = 0; mf < 2; ++mf){
#pragma unroll
          for (int r = 0; r < 4; ++r){
            const int row = (gb + mf) * 16 + ((l >> 4) << 2) + r;
            const float gi = acc[mf][0][r] + bi0;
            const float gf = acc[mf][1][r] + bi1;
            const float gg = acc[mf][2][r] + bi2;
            const float go = acc[mf][3][r] + bi3;
            const float cn = sigm(gf) * creg[mf][r] + sigm(gi) * tanh_(gg);
            out[row * 1024 + col] = sigm(go) * tanh_(cn);
            out[262144 + row * 1024 + col] = cn;
          }
        }
      }
      asm volatile("s_waitcnt vmcnt(0)" ::: "memory");
      __syncthreads();
      if (tid == 0){
        if (useFence) __builtin_amdgcn_fence(__ATOMIC_RELEASE, "agent");
        __hip_atomic_fetch_add(ctrB, 1, __ATOMIC_RELAXED, AGENT);
      }
    }
  }
}

extern "C" void kernel_launch(void* const* d_in, const int* in_sizes, int n_in,
                              void* d_out, int out_size, void* d_ws, size_t ws_size,
                              hipStream_t stream){
  const float* x    = (const float*)d_in[0];
  const float* Wlin = (const float*)d_in[1];
  const float* blin = (const float*)d_in[2];
  const float* Wih1 = (const float*)d_in[3];
  const float* Whh1 = (const float*)d_in[4];
  const float* bih1 = (const float*)d_in[5];
  const float* bhh1 = (const float*)d_in[6];
  const float* Wih2 = (const float*)d_in[7];
  const float* Whh2 = (const float*)d_in[8];
  const float* bih2 = (const float*)d_in[9];
  const float* bhh2 = (const float*)d_in[10];
  char* ws = (char*)d_ws;

  const size_t SLOT = 524288;
  int d1 = 100, d2 = 100, useFence = 0;
  const size_t need = 1024 + 200 * SLOT + 3 * 8388608ull + 524288 + 3276800 + 32768;
  if (ws_size < need){ d1 = 3; d2 = 2; useFence = 1; }   // fallback: fenced, bounded-ahead

  size_t off = 0;
  int*   ctrA  = (int*)(ws + off);  off += 128;
  int*   ctrB  = (int*)(ws + off);  off = 1024;
  USH*   hA2   = (USH*)(ws + off);  off += (size_t)d2 * SLOT;
  USH*   hA1   = (USH*)(ws + off);  off += (size_t)d1 * SLOT;
  USH*   Wpk1  = (USH*)(ws + off);  off += 8388608;
  USH*   Wpk2a = (USH*)(ws + off);  off += 8388608;
  USH*   Wpk2b = (USH*)(ws + off);  off += 8388608;
  USH*   Wcpk  = (USH*)(ws + off);  off += 524288;
  USH*   xpk   = (USH*)(ws + off);  off += 3276800;
  float* bc    = (float*)(ws + off); off += 16384;
  float* b2    = (float*)(ws + off);

  hipMemsetAsync(ws, 0, 1024 + SLOT, stream);            // ctrs + h2 slot 0
  k_fold<<<4096, 64, 0, stream>>>(Wih1, Wlin, blin, bih1, bhh1, Wcpk, bc);
  k_pack<<<2048, 256, 0, stream>>>(Whh1, Wih2, Whh2, bih2, bhh2, Wpk1, Wpk2a, Wpk2b, b2);
  k_xpk<<<1024, 256, 0, stream>>>(x, xpk);

  float* outp = (float*)d_out;
  void* args[] = {&hA1, &hA2, &ctrA, &ctrB, &Wpk1, &Wpk2a, &Wpk2b, &Wcpk, &xpk, &bc, &b2, &outp,
                  &d1, &d2, &useFence};
  hipError_t e = hipLaunchCooperativeKernel((void*)k_persist, dim3(256), dim3(256), args, 0, stream);
  if (e != hipSuccess){
    k_persist<<<dim3(256), dim3(256), 0, stream>>>(hA1, hA2, ctrA, ctrB, Wpk1, Wpk2a, Wpk2b,
                                                   Wcpk, xpk, bc, b2, outp, d1, d2, useFence);
  }
}